// Round 15
// baseline (2060.878 us; speedup 1.0000x reference)
//
#include <hip/hip_runtime.h>

// LSTM 2-layer — DUAL-ENGINE: 512 blocks x 256 thr; blocks [0,256) run
// layer0 for batch row b, blocks [256,512) run layer1 for row b-256. Two
// blocks co-resident per CU (VGPR 2x256 = file, LDS 2x45KB), fully ASYNC
// (separate barriers) -> each block's serial chain is hidden by the sibling.
// R13 (1,550us) was chain-bound with all 8 waves barrier-locked per step;
// R14 proved single-block 2-layer weight residency is impossible (LDS
// weight streaming = pipe-bound). Here each block pins its layer's Whh
// fully in VGPRs (32 frags = 128 regs; grant law 65536/256thr = 256, R12-
// proven) — zero weight reads in the serial loop.
// Handoff: L0 writes h0 chunks (fp16 hi|lo packed u32) to a FULL-SIZE
// global buffer in d_ws (no backpressure => deadlock-free under ANY block
// scheduling) + per-row produced-counter flags (agent-scope release/acquire
// handles cross-XCD L2 non-coherence; %8 dispatch makes pairs same-XCD as
// a perf bonus). Publish is a bulk copy AFTER the serial loop (per-step
// barriers never wait on global stores). Flags memset per launch (graph-
// replay safe).
// Serial step (both engines): R12's 8-tile/wave geometry + R13's N-packed
// hi/lo (even cols = h_hi, odd = h_lo; combine via shfl_xor(1)) = 32 MFMA +
// 4 ds_read_b128 per wave per step; double epilogue (2 units/lane);
// sigmoid 0.5-prescale folded into pack_w + bias (R12-proven).
// d_ws requirement: 134,677,504 B (weights 448KB + h0 stream 128MB + flags).

typedef __attribute__((ext_vector_type(4))) float f32x4;
typedef _Float16 f16x8 __attribute__((ext_vector_type(8)));
typedef short s16x8 __attribute__((ext_vector_type(8)));

#define NB    256
#define TSEQ  1024
#define II    64
#define HH    128
#define G4    512
#define TC    16
#define NCH   (TSEQ/TC)
#define SCL   0.0009765625f   // 2^-10
#define SCLI  1024.f          // 2^10

// ws frag regions (16B units). idx = region + ((w*8+t8)*NKS+s)*64 + lane.
#define F_WHH0  0
#define F_WHH1  8192
#define F_WIH1  16384
#define F_WIH0  24576
#define F_TOTAL 28672

#define H0G_OFF   458752ULL
#define H0G_WORDS (256ULL*1024ULL*128ULL)           // u32 words (128 MiB)
#define FLAG_OFF  (H0G_OFF + H0G_WORDS*4ULL)        // 134,676,480
#define WS_NEEDED (FLAG_OFF + 1024ULL)              // 134,677,504

#define KEEP4I(v) asm volatile("" : "+v"((v).x), "+v"((v).y), "+v"((v).z), "+v"((v).w))

__device__ __forceinline__ float tanh_f(float x){
    float ax = fabsf(x);
    float e  = __expf(2.f*ax);
    float t  = 1.f - 2.f*__builtin_amdgcn_rcpf(e + 1.f);
    return copysignf(t, x);
}
__device__ __forceinline__ f32x4 mfma16(int4 a, f16x8 b, f32x4 c){
    return __builtin_amdgcn_mfma_f32_16x16x32_f16(
        __builtin_bit_cast(f16x8, a), b, c, 0, 0, 0);
}
__device__ __forceinline__ f16x8 ldb(const _Float16* p){
    return __builtin_bit_cast(f16x8, *(const int4*)p);
}
__device__ __forceinline__ void unpack8(int4 v0, int4 v1, f16x8& bh, f16x8& bl){
    s16x8 hb, lb;
    hb[0]=(short)v0.x; lb[0]=(short)(((unsigned)v0.x)>>16);
    hb[1]=(short)v0.y; lb[1]=(short)(((unsigned)v0.y)>>16);
    hb[2]=(short)v0.z; lb[2]=(short)(((unsigned)v0.z)>>16);
    hb[3]=(short)v0.w; lb[3]=(short)(((unsigned)v0.w)>>16);
    hb[4]=(short)v1.x; lb[4]=(short)(((unsigned)v1.x)>>16);
    hb[5]=(short)v1.y; lb[5]=(short)(((unsigned)v1.y)>>16);
    hb[6]=(short)v1.z; lb[6]=(short)(((unsigned)v1.z)>>16);
    hb[7]=(short)v1.w; lb[7]=(short)(((unsigned)v1.w)>>16);
    bh = __builtin_bit_cast(f16x8, hb);
    bl = __builtin_bit_cast(f16x8, lb);
}

// ---------------- pack kernel (R12-proven): fp32 -> fp16 A-fragments -------
// row = (t8>>1)*128 + w*32 + (t8&1)*16 + (lane&15); k = s*32 + (lane>>4)*8+j.
// Non-g gate rows pre-scaled by 0.5 (sigmoid via tanh(x/2)).
__global__ void pack_w(const float* __restrict__ Wih0, const float* __restrict__ Whh0,
                       const float* __restrict__ Wih1, const float* __restrict__ Whh1,
                       int4* __restrict__ ws)
{
    int fid = blockIdx.x * 256 + threadIdx.x;
    if (fid >= F_TOTAL) return;
    const float* src; int nks; int rb;
    if (fid < F_WHH1)      { src = Whh0; nks = 4; rb = fid; }
    else if (fid < F_WIH1) { src = Whh1; nks = 4; rb = fid - F_WHH1; }
    else if (fid < F_WIH0) { src = Wih1; nks = 4; rb = fid - F_WIH1; }
    else                   { src = Wih0; nks = 2; rb = fid - F_WIH0; }
    int lane = rb & 63;
    int rem  = rb >> 6;
    int s    = rem % nks;
    int t8   = (rem / nks) & 7;
    int w    = rem / (nks * 8);
    int gate = t8 >> 1;
    int row  = gate * 128 + w * 32 + (t8 & 1) * 16 + (lane & 15);
    float scale = (gate == 2) ? 1.f : 0.5f;
    int K    = nks * 32;
    int k0   = s * 32 + (lane >> 4) * 8;
    const float* p = src + (size_t)row * K + k0;
    unsigned short us[8];
    #pragma unroll
    for (int j = 0; j < 8; ++j)
        us[j] = __builtin_bit_cast(unsigned short, (_Float16)(p[j] * scale));
    int4 o;
    o.x = (int)((unsigned)us[0] | ((unsigned)us[1] << 16));
    o.y = (int)((unsigned)us[2] | ((unsigned)us[3] << 16));
    o.z = (int)((unsigned)us[4] | ((unsigned)us[5] << 16));
    o.w = (int)((unsigned)us[6] | ((unsigned)us[7] << 16));
    ws[fid] = o;
}

// ---------------- dual-engine persistent kernel ----------------------------
__global__ __launch_bounds__(256, 1)
void lstm_dual(const float* __restrict__ x,
               const float* __restrict__ bih0, const float* __restrict__ bhh0,
               const float* __restrict__ bih1, const float* __restrict__ bhh1,
               const float* __restrict__ Wlin, const float* __restrict__ blin,
               const int4* __restrict__ ws,
               unsigned* __restrict__ h0g,
               int* __restrict__ prod,
               float* __restrict__ out)
{
    const int tid  = threadIdx.x;
    const int lane = tid & 63;
    const int w    = tid >> 6;          // wave 0..3
    const int lm   = lane & 15;
    const int lk   = lane >> 4;
    const int gsel = lm >> 2;
    const int usel = lm & 3;
    const int uA   = w*32 + lk*4 + usel;
    const int uB   = uA + 16;
    const int xprA = gsel*128 + w*32 + lk*4 + usel;
    const int base = lane & 0x33;
    const bool writer = (gsel == 0);
    const bool is_g   = (gsel == 2);
    const bool odd    = (lane & 1);

    __shared__ __align__(16) char smem[46080];

    if (blockIdx.x < NB) {
        // =================== LAYER-0 ENGINE ===================
        const int row = blockIdx.x;
        float    (*xp0)[G4]   = (float(*)[G4])smem;                 // 32,768
        _Float16 (*h0_hi)[HH] = (_Float16(*)[HH])(smem + 32768);    //  4,352
        _Float16 (*h0_lo)[HH] = (_Float16(*)[HH])(smem + 37120);    //  4,352
        _Float16 (*xc_hi)[72] = (_Float16(*)[72])(smem + 41472);    //  2,304
        _Float16 (*xc_lo)[72] = (_Float16(*)[72])(smem + 43776);    //  2,304

        if (tid < HH){ h0_hi[0][tid] = (_Float16)0.f; h0_lo[0][tid] = (_Float16)0.f; }
        float cA = 0.f, cB = 0.f;
        const float* xb = x + (size_t)row * TSEQ * II;
        __syncthreads();

        #pragma unroll 1
        for (int ch = 0; ch < NCH; ++ch){
            // ---- stage x chunk as fp16 hi + scaled lo; carry h0 ----
            #pragma unroll
            for (int j = 0; j < 4; ++j){
                int i = tid + 256*j;
                float v = xb[(size_t)ch*TC*II + i];
                _Float16 a = (_Float16)v;
                xc_hi[i>>6][i&63] = a;
                xc_lo[i>>6][i&63] = (_Float16)((v - (float)a)*SCLI);
            }
            if (ch > 0 && tid < HH){
                h0_hi[0][tid] = h0_hi[TC][tid];
                h0_lo[0][tid] = h0_lo[TC][tid];
            }
            __syncthreads();

            // ---- proj xp0 (K=64, 16 timestep-cols) ----
            {
                f32x4 acc[8], accL[8];
                #pragma unroll
                for (int i = 0; i < 8; ++i){
                    acc[i]  = (f32x4){0.f,0.f,0.f,0.f};
                    accL[i] = (f32x4){0.f,0.f,0.f,0.f};
                }
                #pragma unroll
                for (int s = 0; s < 2; ++s){
                    f16x8 bh = ldb(&xc_hi[lm][s*32 + lk*8]);
                    f16x8 bl = ldb(&xc_lo[lm][s*32 + lk*8]);
                    int4 ah[8];
                    #pragma unroll
                    for (int t8 = 0; t8 < 8; ++t8)
                        ah[t8] = ws[F_WIH0 + (((w*8 + t8)*2 + s) << 6) + lane];
                    #pragma unroll
                    for (int t8 = 0; t8 < 8; ++t8) acc[t8]  = mfma16(ah[t8], bh, acc[t8]);
                    #pragma unroll
                    for (int t8 = 0; t8 < 8; ++t8) accL[t8] = mfma16(ah[t8], bl, accL[t8]);
                }
                #pragma unroll
                for (int t8 = 0; t8 < 8; ++t8){
                    int rowb = (t8>>1)*128 + w*32 + (t8&1)*16 + lk*4;
                    float sc = ((t8>>1) == 2) ? 1.f : 0.5f;
                    f32x4 bs = (*(const f32x4*)(bih0+rowb) + *(const f32x4*)(bhh0+rowb)) * sc;
                    *(f32x4*)&xp0[lm][rowb] = acc[t8] + accL[t8]*SCL + bs;
                }
            }
            __syncthreads();

            // ---- serial 16 steps (N-packed, 8 tiles/wave) ----
            int4 Ahi[8][4];
            #pragma unroll
            for (int t8 = 0; t8 < 8; ++t8)
                #pragma unroll
                for (int s = 0; s < 4; ++s)
                    Ahi[t8][s] = ws[F_WHH0 + (((w*8 + t8)*4 + s) << 6) + lane];
            #pragma unroll
            for (int t8 = 0; t8 < 8; ++t8)
                #pragma unroll
                for (int s = 0; s < 4; ++s) KEEP4I(Ahi[t8][s]);

            #pragma unroll 1
            for (int t = 0; t < TC; ++t){
                const _Float16* bp = odd ? &h0_lo[t][0] : &h0_hi[t][0];
                float xpvA = xp0[t][xprA];
                float xpvB = xp0[t][xprA + 16];
                f32x4 acc[8];
                #pragma unroll
                for (int i = 0; i < 8; ++i) acc[i] = (f32x4){0.f,0.f,0.f,0.f};
                #pragma unroll
                for (int s = 0; s < 4; ++s){
                    f16x8 bv = ldb(&bp[s*32 + lk*8]);
                    #pragma unroll
                    for (int t8 = 0; t8 < 8; ++t8) acc[t8] = mfma16(Ahi[t8][s], bv, acc[t8]);
                }
                float ownA, othA, ownB, othB;
                {
                    f32x4 p01 = (gsel & 1) ? acc[2] : acc[0];
                    f32x4 p23 = (gsel & 1) ? acc[6] : acc[4];
                    f32x4 ps  = (gsel & 2) ? p23 : p01;
                    float a01 = (usel & 1) ? ps[1] : ps[0];
                    float a23 = (usel & 1) ? ps[3] : ps[2];
                    ownA = (usel & 2) ? a23 : a01;
                    float b01 = (usel & 1) ? ps[0] : ps[1];
                    float b23 = (usel & 1) ? ps[2] : ps[3];
                    othA = (usel & 2) ? b23 : b01;
                }
                {
                    f32x4 p01 = (gsel & 1) ? acc[3] : acc[1];
                    f32x4 p23 = (gsel & 1) ? acc[7] : acc[5];
                    f32x4 ps  = (gsel & 2) ? p23 : p01;
                    float a01 = (usel & 1) ? ps[1] : ps[0];
                    float a23 = (usel & 1) ? ps[3] : ps[2];
                    ownB = (usel & 2) ? a23 : a01;
                    float b01 = (usel & 1) ? ps[0] : ps[1];
                    float b23 = (usel & 1) ? ps[2] : ps[3];
                    othB = (usel & 2) ? b23 : b01;
                }
                float recvA = __shfl_xor(othA, 1);
                float recvB = __shfl_xor(othB, 1);
                float preA = (odd ? recvA + SCL*ownA : ownA + SCL*recvA) + xpvA;
                float preB = (odd ? recvB + SCL*ownB : ownB + SCL*recvB) + xpvB;
                float zA = tanh_f(preA); float yA = is_g ? zA : 0.5f*zA + 0.5f;
                float zB = tanh_f(preB); float yB = is_g ? zB : 0.5f*zB + 0.5f;
                float giA=__shfl(yA,base), gfA=__shfl(yA,base|4), ggA=__shfl(yA,base|8), goA=__shfl(yA,base|12);
                float giB=__shfl(yB,base), gfB=__shfl(yB,base|4), ggB=__shfl(yB,base|8), goB=__shfl(yB,base|12);
                cA = gfA*cA + giA*ggA;  float hA = goA * tanh_f(cA);
                cB = gfB*cB + giB*ggB;  float hB = goB * tanh_f(cB);
                _Float16 hfA = (_Float16)hA, hfB = (_Float16)hB;
                _Float16 hlA = (_Float16)((hA - (float)hfA)*SCLI);
                _Float16 hlB = (_Float16)((hB - (float)hfB)*SCLI);
                if (writer){
                    h0_hi[t+1][uA] = hfA; h0_lo[t+1][uA] = hlA;
                    h0_hi[t+1][uB] = hfB; h0_lo[t+1][uB] = hlB;
                }
                __syncthreads();
            }

            // ---- publish chunk to global (bulk, off the serial chain) ----
            {
                size_t gbase = ((size_t)row*TSEQ + (size_t)ch*TC)*HH;
                #pragma unroll
                for (int k = 0; k < 8; ++k){
                    int idx = tid*8 + k;
                    int t = idx >> 7, u = idx & 127;
                    unsigned ph = (unsigned)__builtin_bit_cast(unsigned short, h0_hi[t+1][u]);
                    unsigned pl = (unsigned)__builtin_bit_cast(unsigned short, h0_lo[t+1][u]);
                    h0g[gbase + idx] = ph | (pl << 16);
                }
            }
            __syncthreads();   // drains all waves' global stores (vmcnt 0)
            if (tid == 0)
                __hip_atomic_store(&prod[row], ch+1, __ATOMIC_RELEASE,
                                   __HIP_MEMORY_SCOPE_AGENT);
        }
    } else {
        // =================== LAYER-1 ENGINE ===================
        const int row = blockIdx.x - NB;
        float    (*xp1)[G4]   = (float(*)[G4])smem;                 // 32,768
        _Float16 (*h1_hi)[HH] = (_Float16(*)[HH])(smem + 32768);    //    512
        _Float16 (*h1_lo)[HH] = (_Float16(*)[HH])(smem + 33280);    //    512
        float*    h1f         = (float*)(smem + 33792);             //    512

        if (tid < HH){ h1_hi[0][tid] = (_Float16)0.f; h1_lo[0][tid] = (_Float16)0.f;
                       h1f[tid] = 0.f; }
        float cA = 0.f, cB = 0.f;
        __syncthreads();

        #pragma unroll 1
        for (int ch = 0; ch < NCH; ++ch){
            // ---- wait for h0 chunk (relaxed spin + final acquire) ----
            {
                int v = __hip_atomic_load(&prod[row], __ATOMIC_RELAXED,
                                          __HIP_MEMORY_SCOPE_AGENT);
                while (v < ch+1){
                    __builtin_amdgcn_s_sleep(8);
                    v = __hip_atomic_load(&prod[row], __ATOMIC_RELAXED,
                                          __HIP_MEMORY_SCOPE_AGENT);
                }
                (void)__hip_atomic_load(&prod[row], __ATOMIC_ACQUIRE,
                                        __HIP_MEMORY_SCOPE_AGENT);
            }
            // ---- proj xp1 from global h0 chunk (K=128, 16 t-cols) ----
            {
                f32x4 acc[8], accL[8];
                #pragma unroll
                for (int i = 0; i < 8; ++i){
                    acc[i]  = (f32x4){0.f,0.f,0.f,0.f};
                    accL[i] = (f32x4){0.f,0.f,0.f,0.f};
                }
                size_t gbase = ((size_t)row*TSEQ + (size_t)ch*TC + lm)*HH;
                #pragma unroll
                for (int s = 0; s < 4; ++s){
                    const int4* gp = (const int4*)(h0g + gbase + s*32 + lk*8);
                    int4 v0 = gp[0], v1 = gp[1];
                    f16x8 bh, bl;
                    unpack8(v0, v1, bh, bl);
                    int4 ah[8];
                    #pragma unroll
                    for (int t8 = 0; t8 < 8; ++t8)
                        ah[t8] = ws[F_WIH1 + (((w*8 + t8)*4 + s) << 6) + lane];
                    #pragma unroll
                    for (int t8 = 0; t8 < 8; ++t8) acc[t8]  = mfma16(ah[t8], bh, acc[t8]);
                    #pragma unroll
                    for (int t8 = 0; t8 < 8; ++t8) accL[t8] = mfma16(ah[t8], bl, accL[t8]);
                }
                #pragma unroll
                for (int t8 = 0; t8 < 8; ++t8){
                    int rowb = (t8>>1)*128 + w*32 + (t8&1)*16 + lk*4;
                    float sc = ((t8>>1) == 2) ? 1.f : 0.5f;
                    f32x4 bs = (*(const f32x4*)(bih1+rowb) + *(const f32x4*)(bhh1+rowb)) * sc;
                    *(f32x4*)&xp1[lm][rowb] = acc[t8] + accL[t8]*SCL + bs;
                }
            }
            __syncthreads();

            // ---- serial 16 steps ----
            int4 Ahi[8][4];
            #pragma unroll
            for (int t8 = 0; t8 < 8; ++t8)
                #pragma unroll
                for (int s = 0; s < 4; ++s)
                    Ahi[t8][s] = ws[F_WHH1 + (((w*8 + t8)*4 + s) << 6) + lane];
            #pragma unroll
            for (int t8 = 0; t8 < 8; ++t8)
                #pragma unroll
                for (int s = 0; s < 4; ++s) KEEP4I(Ahi[t8][s]);

            #pragma unroll 1
            for (int t = 0; t < TC; ++t){
                const _Float16* bp = odd ? &h1_lo[t&1][0] : &h1_hi[t&1][0];
                float xpvA = xp1[t][xprA];
                float xpvB = xp1[t][xprA + 16];
                f32x4 acc[8];
                #pragma unroll
                for (int i = 0; i < 8; ++i) acc[i] = (f32x4){0.f,0.f,0.f,0.f};
                #pragma unroll
                for (int s = 0; s < 4; ++s){
                    f16x8 bv = ldb(&bp[s*32 + lk*8]);
                    #pragma unroll
                    for (int t8 = 0; t8 < 8; ++t8) acc[t8] = mfma16(Ahi[t8][s], bv, acc[t8]);
                }
                float ownA, othA, ownB, othB;
                {
                    f32x4 p01 = (gsel & 1) ? acc[2] : acc[0];
                    f32x4 p23 = (gsel & 1) ? acc[6] : acc[4];
                    f32x4 ps  = (gsel & 2) ? p23 : p01;
                    float a01 = (usel & 1) ? ps[1] : ps[0];
                    float a23 = (usel & 1) ? ps[3] : ps[2];
                    ownA = (usel & 2) ? a23 : a01;
                    float b01 = (usel & 1) ? ps[0] : ps[1];
                    float b23 = (usel & 1) ? ps[2] : ps[3];
                    othA = (usel & 2) ? b23 : b01;
                }
                {
                    f32x4 p01 = (gsel & 1) ? acc[3] : acc[1];
                    f32x4 p23 = (gsel & 1) ? acc[7] : acc[5];
                    f32x4 ps  = (gsel & 2) ? p23 : p01;
                    float a01 = (usel & 1) ? ps[1] : ps[0];
                    float a23 = (usel & 1) ? ps[3] : ps[2];
                    ownB = (usel & 2) ? a23 : a01;
                    float b01 = (usel & 1) ? ps[0] : ps[1];
                    float b23 = (usel & 1) ? ps[2] : ps[3];
                    othB = (usel & 2) ? b23 : b01;
                }
                float recvA = __shfl_xor(othA, 1);
                float recvB = __shfl_xor(othB, 1);
                float preA = (odd ? recvA + SCL*ownA : ownA + SCL*recvA) + xpvA;
                float preB = (odd ? recvB + SCL*ownB : ownB + SCL*recvB) + xpvB;
                float zA = tanh_f(preA); float yA = is_g ? zA : 0.5f*zA + 0.5f;
                float zB = tanh_f(preB); float yB = is_g ? zB : 0.5f*zB + 0.5f;
                float giA=__shfl(yA,base), gfA=__shfl(yA,base|4), ggA=__shfl(yA,base|8), goA=__shfl(yA,base|12);
                float giB=__shfl(yB,base), gfB=__shfl(yB,base|4), ggB=__shfl(yB,base|8), goB=__shfl(yB,base|12);
                cA = gfA*cA + giA*ggA;  float hA = goA * tanh_f(cA);
                cB = gfB*cB + giB*ggB;  float hB = goB * tanh_f(cB);
                _Float16 hfA = (_Float16)hA, hfB = (_Float16)hB;
                _Float16 hlA = (_Float16)((hA - (float)hfA)*SCLI);
                _Float16 hlB = (_Float16)((hB - (float)hfB)*SCLI);
                if (writer){
                    h1_hi[(t+1)&1][uA] = hfA; h1_lo[(t+1)&1][uA] = hlA; h1f[uA] = hA;
                    h1_hi[(t+1)&1][uB] = hfB; h1_lo[(t+1)&1][uB] = hlB; h1f[uB] = hB;
                }
                __syncthreads();
            }
        }

        // ---- final linear: out[row] = h1 . Wlin[0,:] + blin ----
        if (tid < 64){
            float s = h1f[tid]*Wlin[tid] + h1f[tid+64]*Wlin[tid+64];
            #pragma unroll
            for (int off = 32; off; off >>= 1) s += __shfl_down(s, off);
            if (tid == 0) out[row] = s + blin[0];
        }
    }
}

extern "C" void kernel_launch(void* const* d_in, const int* in_sizes, int n_in,
                              void* d_out, int out_size, void* d_ws, size_t ws_size,
                              hipStream_t stream)
{
    const float* x    = (const float*)d_in[0];
    const float* Wih0 = (const float*)d_in[1];
    const float* Whh0 = (const float*)d_in[2];
    const float* bih0 = (const float*)d_in[3];
    const float* bhh0 = (const float*)d_in[4];
    const float* Wih1 = (const float*)d_in[5];
    const float* Whh1 = (const float*)d_in[6];
    const float* bih1 = (const float*)d_in[7];
    const float* bhh1 = (const float*)d_in[8];
    const float* Wlin = (const float*)d_in[9];
    const float* blin = (const float*)d_in[10];

    if (ws_size < WS_NEEDED) return;   // loud deterministic failure if ws too small

    char* wsb = (char*)d_ws;
    int4*     ws   = (int4*)wsb;
    unsigned* h0g  = (unsigned*)(wsb + H0G_OFF);
    int*      prod = (int*)(wsb + FLAG_OFF);

    hipMemsetAsync(prod, 0, 1024, stream);
    hipLaunchKernelGGL(pack_w, dim3(F_TOTAL/256), dim3(256), 0, stream,
                       Wih0, Whh0, Wih1, Whh1, ws);
    hipLaunchKernelGGL(lstm_dual, dim3(2*NB), dim3(256), 0, stream,
                       x, bih0, bhh0, bih1, bhh1, Wlin, blin,
                       ws, h0g, prod, (float*)d_out);
}

// Round 17
// 1691.842 us; speedup vs baseline: 1.2181x; 1.2181x over previous
//
#include <hip/hip_runtime.h>

// LSTM 2-layer — DUAL-ENGINE v2: 512 blocks x 512 thr. Blocks [0,256) run
// layer0 of batch row b; [256,512) run layer1 of row b-256. R15 proved the
// dataflow (bit-identical absmax) but its 256-VGPR blocks never co-resided
// (Occupancy 12% -> engines serialized). v2 uses the 4x-proven regime:
// 512thr -> 128-VGPR grant, 46.6KB LDS -> TWO blocks per CU (16 waves, 4/
// SIMD, VGPR 4x128=512/SIMD exact). Each engine = R13's serial structure
// verbatim (4 tiles/wave gate-major, N-packed hi/lo cols, shfl_xor combine,
// wave-local c-update). Two independent 1024-step chains interleave per CU.
// Handoff (R15-validated): L0 publishes h0 chunks (fp16 hi|lo u32) to a
// FULL-SIZE global buffer in d_ws (no backpressure = deadlock-free under
// any scheduling) + per-row produced-counters, agent-scope release/acquire
// (cross-XCD safe; b and b+256 share an XCD via %8 as a perf bonus).
// R17 = R16 with the serial_steps xp-parameter type fixed (compile error:
// smem-cast float(*)[G4] vs declared float(&)[TC][G4]).
// d_ws requirement: 134,677,504 B.

typedef __attribute__((ext_vector_type(4))) float f32x4;
typedef _Float16 f16x8 __attribute__((ext_vector_type(8)));
typedef short s16x8 __attribute__((ext_vector_type(8)));

#define NB    256
#define TSEQ  1024
#define II    64
#define HH    128
#define G4    512
#define TC    16
#define NCH   (TSEQ/TC)
#define SCL   0.0009765625f   // 2^-10
#define SCLI  1024.f          // 2^10

// ws frag regions (16B units), R13 layout: idx = region + ((w*4+t4)*NKS+s)*64 + lane.
#define F_WHH0  0
#define F_WHH1  8192
#define F_WIH1  16384
#define F_WIH0  24576
#define F_TOTAL 28672

#define H0G_OFF   458752ULL
#define H0G_WORDS (256ULL*1024ULL*128ULL)
#define FLAG_OFF  (H0G_OFF + H0G_WORDS*4ULL)
#define WS_NEEDED (FLAG_OFF + 1024ULL)   // 134,677,504

#define KEEP4I(v) asm volatile("" : "+v"((v).x), "+v"((v).y), "+v"((v).z), "+v"((v).w))

__device__ __forceinline__ float tanh_f(float x){
    float ax = fabsf(x);
    float e  = __expf(2.f*ax);
    float t  = 1.f - 2.f*__builtin_amdgcn_rcpf(e + 1.f);
    return copysignf(t, x);
}
__device__ __forceinline__ f32x4 mfma16(int4 a, f16x8 b, f32x4 c){
    return __builtin_amdgcn_mfma_f32_16x16x32_f16(
        __builtin_bit_cast(f16x8, a), b, c, 0, 0, 0);
}
__device__ __forceinline__ f16x8 ldb(const _Float16* p){
    return __builtin_bit_cast(f16x8, *(const int4*)p);
}
__device__ __forceinline__ void unpack8(int4 v0, int4 v1, f16x8& bh, f16x8& bl){
    s16x8 hb, lb;
    hb[0]=(short)v0.x; lb[0]=(short)(((unsigned)v0.x)>>16);
    hb[1]=(short)v0.y; lb[1]=(short)(((unsigned)v0.y)>>16);
    hb[2]=(short)v0.z; lb[2]=(short)(((unsigned)v0.z)>>16);
    hb[3]=(short)v0.w; lb[3]=(short)(((unsigned)v0.w)>>16);
    hb[4]=(short)v1.x; lb[4]=(short)(((unsigned)v1.x)>>16);
    hb[5]=(short)v1.y; lb[5]=(short)(((unsigned)v1.y)>>16);
    hb[6]=(short)v1.z; lb[6]=(short)(((unsigned)v1.z)>>16);
    hb[7]=(short)v1.w; lb[7]=(short)(((unsigned)v1.w)>>16);
    bh = __builtin_bit_cast(f16x8, hb);
    bl = __builtin_bit_cast(f16x8, lb);
}

// ---------------- pack kernel (R13 verbatim): fp32 -> fp16 A-fragments -----
// row = t4*128 + w*16 + (lane&15); k = s*32 + (lane>>4)*8 + j.
__global__ void pack_w(const float* __restrict__ Wih0, const float* __restrict__ Whh0,
                       const float* __restrict__ Wih1, const float* __restrict__ Whh1,
                       int4* __restrict__ ws)
{
    int fid = blockIdx.x * 256 + threadIdx.x;
    if (fid >= F_TOTAL) return;
    const float* src; int nks; int rb;
    if (fid < F_WHH1)      { src = Whh0; nks = 4; rb = fid; }
    else if (fid < F_WIH1) { src = Whh1; nks = 4; rb = fid - F_WHH1; }
    else if (fid < F_WIH0) { src = Wih1; nks = 4; rb = fid - F_WIH1; }
    else                   { src = Wih0; nks = 2; rb = fid - F_WIH0; }
    int lane = rb & 63;
    int rem  = rb >> 6;
    int s    = rem % nks;
    int t    = (rem / nks) & 3;
    int w    = rem / (nks * 4);
    int row  = t * 128 + w * 16 + (lane & 15);
    int K    = nks * 32;
    int k0   = s * 32 + (lane >> 4) * 8;
    const float* p = src + (size_t)row * K + k0;
    unsigned short us[8];
    #pragma unroll
    for (int j = 0; j < 8; ++j)
        us[j] = __builtin_bit_cast(unsigned short, (_Float16)p[j]);
    int4 o;
    o.x = (int)((unsigned)us[0] | ((unsigned)us[1] << 16));
    o.y = (int)((unsigned)us[2] | ((unsigned)us[3] << 16));
    o.z = (int)((unsigned)us[4] | ((unsigned)us[5] << 16));
    o.w = (int)((unsigned)us[6] | ((unsigned)us[7] << 16));
    ws[fid] = o;
}

// ---------------- shared serial-step body (R13 verbatim math) --------------
struct LaneCtx {
    int gsel, usel, u, xpr, base;
    bool writer, is_g, odd;
    int lk;
};

template<bool PING>
__device__ __forceinline__ void serial_steps(
    const LaneCtx& L, const int4 (&Ahi)[4][4],
    float (*xp)[G4],
    _Float16* hh_rd_base, _Float16* hl_rd_base, int rd_stride,
    _Float16* hh_wr_base, _Float16* hl_wr_base, int wr_stride,
    float* h1f, float& c)
{
    #pragma unroll 1
    for (int t = 0; t < TC; ++t){
        int rs = PING ? (t & 1) : t;
        int wsl = PING ? ((t+1) & 1) : (t+1);
        const _Float16* bp = L.odd ? (hl_rd_base + rs*rd_stride)
                                   : (hh_rd_base + rs*rd_stride);
        float xpv = xp[t][L.xpr];
        f32x4 acc[4];
        #pragma unroll
        for (int t4 = 0; t4 < 4; ++t4) acc[t4] = (f32x4){0.f,0.f,0.f,0.f};
        #pragma unroll
        for (int s = 0; s < 4; ++s){
            f16x8 bv = ldb(&bp[s*32 + L.lk*8]);
            #pragma unroll
            for (int t4 = 0; t4 < 4; ++t4) acc[t4] = mfma16(Ahi[t4][s], bv, acc[t4]);
        }
        f32x4 ps;
        {
            f32x4 p01 = (L.gsel & 1) ? acc[1] : acc[0];
            f32x4 p23 = (L.gsel & 1) ? acc[3] : acc[2];
            ps = (L.gsel & 2) ? p23 : p01;
        }
        float own, oth;
        {
            float a01 = (L.usel & 1) ? ps[1] : ps[0];
            float a23 = (L.usel & 1) ? ps[3] : ps[2];
            own = (L.usel & 2) ? a23 : a01;
            float b01 = (L.usel & 1) ? ps[0] : ps[1];
            float b23 = (L.usel & 1) ? ps[2] : ps[3];
            oth = (L.usel & 2) ? b23 : b01;
        }
        float recv = __shfl_xor(oth, 1);
        float pre  = (L.odd ? (recv + SCL*own) : (own + SCL*recv)) + xpv;
        float z    = tanh_f(L.is_g ? pre : 0.5f*pre);
        float y    = L.is_g ? z : 0.5f*z + 0.5f;
        float gi = __shfl(y, L.base);
        float gf = __shfl(y, L.base | 4);
        float gg = __shfl(y, L.base | 8);
        float go = __shfl(y, L.base | 12);
        c = gf*c + gi*gg;
        float h = go * tanh_f(c);
        _Float16 hf = (_Float16)h;
        _Float16 hl = (_Float16)((h - (float)hf) * SCLI);
        if (L.writer){
            (hh_wr_base + wsl*wr_stride)[L.u] = hf;
            (hl_wr_base + wsl*wr_stride)[L.u] = hl;
            if (h1f) h1f[L.u] = h;
        }
        __syncthreads();
    }
}

// ---------------- dual-engine persistent kernel ----------------------------
__global__ __launch_bounds__(512, 2)
void lstm_dual(const float* __restrict__ x,
               const float* __restrict__ bih0, const float* __restrict__ bhh0,
               const float* __restrict__ bih1, const float* __restrict__ bhh1,
               const float* __restrict__ Wlin, const float* __restrict__ blin,
               const int4* __restrict__ ws,
               unsigned* __restrict__ h0g,
               int* __restrict__ prod,
               float* __restrict__ out)
{
    const int tid  = threadIdx.x;
    const int lane = tid & 63;
    const int w    = tid >> 6;          // wave 0..7
    const int lm   = lane & 15;
    const int lk   = lane >> 4;

    LaneCtx L;
    L.gsel = lm >> 2;  L.usel = lm & 3;  L.lk = lk;
    L.u    = w*16 + lk*4 + L.usel;
    L.xpr  = L.gsel*128 + w*16 + lk*4 + L.usel;
    L.base = lane & 0x33;
    L.writer = (L.gsel == 0);
    L.is_g   = (L.gsel == 2);
    L.odd    = (lane & 1);

    __shared__ __align__(16) char smem[46624];
    float (*xp)[G4] = (float(*)[G4])smem;                       // 32,768

    if (blockIdx.x < NB) {
        // =================== LAYER-0 ENGINE ===================
        const int row = blockIdx.x;
        _Float16 (*h0_hi)[136] = (_Float16(*)[136])(smem + 32768);  // 4,624
        _Float16 (*h0_lo)[136] = (_Float16(*)[136])(smem + 37392);  // 4,624
        _Float16 (*xc_hi)[72]  = (_Float16(*)[72]) (smem + 42016);  // 2,304
        _Float16 (*xc_lo)[72]  = (_Float16(*)[72]) (smem + 44320);  // 2,304

        if (tid < HH){ h0_hi[0][tid] = (_Float16)0.f; h0_lo[0][tid] = (_Float16)0.f; }
        float c0 = 0.f;
        const float* xb = x + (size_t)row * TSEQ * II;
        __syncthreads();

        #pragma unroll 1
        for (int ch = 0; ch < NCH; ++ch){
            // ---- stage x chunk; carry h0 ----
            {
                int i0 = tid, i1 = tid + 512;
                float v0 = xb[(size_t)ch*TC*II + i0];
                float v1 = xb[(size_t)ch*TC*II + i1];
                _Float16 a0 = (_Float16)v0, a1 = (_Float16)v1;
                xc_hi[i0>>6][i0&63] = a0; xc_lo[i0>>6][i0&63] = (_Float16)((v0-(float)a0)*SCLI);
                xc_hi[i1>>6][i1&63] = a1; xc_lo[i1>>6][i1&63] = (_Float16)((v1-(float)a1)*SCLI);
            }
            if (ch > 0 && tid < HH){
                h0_hi[0][tid] = h0_hi[TC][tid];
                h0_lo[0][tid] = h0_lo[TC][tid];
            }
            __syncthreads();

            // ---- proj xp0 (K=64) ----
            {
                f32x4 acc[4], accL[4];
                #pragma unroll
                for (int t4 = 0; t4 < 4; ++t4){
                    acc[t4]  = (f32x4){0.f,0.f,0.f,0.f};
                    accL[t4] = (f32x4){0.f,0.f,0.f,0.f};
                }
                #pragma unroll
                for (int s = 0; s < 2; ++s){
                    f16x8 bh = ldb(&xc_hi[lm][s*32 + lk*8]);
                    f16x8 bl = ldb(&xc_lo[lm][s*32 + lk*8]);
                    int4 ah[4];
                    #pragma unroll
                    for (int t4 = 0; t4 < 4; ++t4)
                        ah[t4] = ws[F_WIH0 + (((w*4 + t4)*2 + s) << 6) + lane];
                    #pragma unroll
                    for (int t4 = 0; t4 < 4; ++t4) acc[t4]  = mfma16(ah[t4], bh, acc[t4]);
                    #pragma unroll
                    for (int t4 = 0; t4 < 4; ++t4) accL[t4] = mfma16(ah[t4], bl, accL[t4]);
                }
                #pragma unroll
                for (int t4 = 0; t4 < 4; ++t4){
                    int rowb = t4*128 + w*16 + lk*4;
                    f32x4 bs = *(const f32x4*)(bih0+rowb) + *(const f32x4*)(bhh0+rowb);
                    *(f32x4*)&xp[lm][rowb] = acc[t4] + accL[t4]*SCL + bs;
                }
            }
            __syncthreads();

            // ---- serial 16 steps ----
            int4 Ahi[4][4];
            #pragma unroll
            for (int t4 = 0; t4 < 4; ++t4)
                #pragma unroll
                for (int s = 0; s < 4; ++s)
                    Ahi[t4][s] = ws[F_WHH0 + (((w*4 + t4)*4 + s) << 6) + lane];
            #pragma unroll
            for (int t4 = 0; t4 < 4; ++t4)
                #pragma unroll
                for (int s = 0; s < 4; ++s) KEEP4I(Ahi[t4][s]);

            serial_steps<false>(L, Ahi, xp,
                                &h0_hi[0][0], &h0_lo[0][0], 136,
                                &h0_hi[0][0], &h0_lo[0][0], 136,
                                nullptr, c0);

            // ---- publish chunk (bulk, off the serial chain) ----
            {
                size_t gbase = ((size_t)row*TSEQ + (size_t)ch*TC)*HH;
                #pragma unroll
                for (int k = 0; k < 4; ++k){
                    int idx = tid + 512*k;
                    int t = idx >> 7, u = idx & 127;
                    unsigned ph = (unsigned)__builtin_bit_cast(unsigned short, h0_hi[t+1][u]);
                    unsigned pl = (unsigned)__builtin_bit_cast(unsigned short, h0_lo[t+1][u]);
                    h0g[gbase + idx] = ph | (pl << 16);
                }
            }
            __syncthreads();
            if (tid == 0)
                __hip_atomic_store(&prod[row], ch+1, __ATOMIC_RELEASE,
                                   __HIP_MEMORY_SCOPE_AGENT);
        }
    } else {
        // =================== LAYER-1 ENGINE ===================
        const int row = blockIdx.x - NB;
        _Float16 (*h1_hi)[HH] = (_Float16(*)[HH])(smem + 32768);   // 512
        _Float16 (*h1_lo)[HH] = (_Float16(*)[HH])(smem + 33280);   // 512
        float*    h1f         = (float*)(smem + 33792);            // 512

        if (tid < HH){ h1_hi[0][tid] = (_Float16)0.f; h1_lo[0][tid] = (_Float16)0.f;
                       h1f[tid] = 0.f; }
        float c1 = 0.f;
        __syncthreads();

        #pragma unroll 1
        for (int ch = 0; ch < NCH; ++ch){
            // ---- wait for h0 chunk ----
            {
                int v = __hip_atomic_load(&prod[row], __ATOMIC_RELAXED,
                                          __HIP_MEMORY_SCOPE_AGENT);
                while (v < ch+1){
                    __builtin_amdgcn_s_sleep(8);
                    v = __hip_atomic_load(&prod[row], __ATOMIC_RELAXED,
                                          __HIP_MEMORY_SCOPE_AGENT);
                }
                (void)__hip_atomic_load(&prod[row], __ATOMIC_ACQUIRE,
                                        __HIP_MEMORY_SCOPE_AGENT);
            }
            // ---- proj xp1 from global h0 chunk (K=128) ----
            {
                f32x4 acc[4], accL[4];
                #pragma unroll
                for (int t4 = 0; t4 < 4; ++t4){
                    acc[t4]  = (f32x4){0.f,0.f,0.f,0.f};
                    accL[t4] = (f32x4){0.f,0.f,0.f,0.f};
                }
                size_t gbase = ((size_t)row*TSEQ + (size_t)ch*TC + lm)*HH;
                #pragma unroll
                for (int s = 0; s < 4; ++s){
                    const int4* gp = (const int4*)(h0g + gbase + s*32 + lk*8);
                    int4 v0 = gp[0], v1 = gp[1];
                    f16x8 bh, bl;
                    unpack8(v0, v1, bh, bl);
                    int4 ah[4];
                    #pragma unroll
                    for (int t4 = 0; t4 < 4; ++t4)
                        ah[t4] = ws[F_WIH1 + (((w*4 + t4)*4 + s) << 6) + lane];
                    #pragma unroll
                    for (int t4 = 0; t4 < 4; ++t4) acc[t4]  = mfma16(ah[t4], bh, acc[t4]);
                    #pragma unroll
                    for (int t4 = 0; t4 < 4; ++t4) accL[t4] = mfma16(ah[t4], bl, accL[t4]);
                }
                #pragma unroll
                for (int t4 = 0; t4 < 4; ++t4){
                    int rowb = t4*128 + w*16 + lk*4;
                    f32x4 bs = *(const f32x4*)(bih1+rowb) + *(const f32x4*)(bhh1+rowb);
                    *(f32x4*)&xp[lm][rowb] = acc[t4] + accL[t4]*SCL + bs;
                }
            }
            __syncthreads();

            // ---- serial 16 steps (ping-pong h1) ----
            int4 Ahi[4][4];
            #pragma unroll
            for (int t4 = 0; t4 < 4; ++t4)
                #pragma unroll
                for (int s = 0; s < 4; ++s)
                    Ahi[t4][s] = ws[F_WHH1 + (((w*4 + t4)*4 + s) << 6) + lane];
            #pragma unroll
            for (int t4 = 0; t4 < 4; ++t4)
                #pragma unroll
                for (int s = 0; s < 4; ++s) KEEP4I(Ahi[t4][s]);

            serial_steps<true>(L, Ahi, xp,
                               &h1_hi[0][0], &h1_lo[0][0], HH,
                               &h1_hi[0][0], &h1_lo[0][0], HH,
                               h1f, c1);
        }

        // ---- final linear ----
        if (tid < 64){
            float s = h1f[tid]*Wlin[tid] + h1f[tid+64]*Wlin[tid+64];
            #pragma unroll
            for (int off = 32; off; off >>= 1) s += __shfl_down(s, off);
            if (tid == 0) out[row] = s + blin[0];
        }
    }
}

extern "C" void kernel_launch(void* const* d_in, const int* in_sizes, int n_in,
                              void* d_out, int out_size, void* d_ws, size_t ws_size,
                              hipStream_t stream)
{
    const float* x    = (const float*)d_in[0];
    const float* Wih0 = (const float*)d_in[1];
    const float* Whh0 = (const float*)d_in[2];
    const float* bih0 = (const float*)d_in[3];
    const float* bhh0 = (const float*)d_in[4];
    const float* Wih1 = (const float*)d_in[5];
    const float* Whh1 = (const float*)d_in[6];
    const float* bih1 = (const float*)d_in[7];
    const float* bhh1 = (const float*)d_in[8];
    const float* Wlin = (const float*)d_in[9];
    const float* blin = (const float*)d_in[10];

    if (ws_size < WS_NEEDED) return;   // loud deterministic failure if ws too small

    char* wsb = (char*)d_ws;
    int4*     ws   = (int4*)wsb;
    unsigned* h0g  = (unsigned*)(wsb + H0G_OFF);
    int*      prod = (int*)(wsb + FLAG_OFF);

    (void)hipMemsetAsync(prod, 0, 1024, stream);
    hipLaunchKernelGGL(pack_w, dim3(F_TOTAL/256), dim3(256), 0, stream,
                       Wih0, Whh0, Wih1, Whh1, ws);
    hipLaunchKernelGGL(lstm_dual, dim3(2*NB), dim3(512), 0, stream,
                       x, bih0, bhh0, bih1, bhh1, Wlin, blin,
                       ws, h0g, prod, (float*)d_out);
}